// Round 9
// baseline (326.868 us; speedup 1.0000x reference)
//
#include <hip/hip_runtime.h>

// MIND-SSC loss, N=2, C=1, D=H=W=128, radius=1, dilation=2.
// Round 9: round-8 structure (memset + fused(+tail combine) + clipped-fallback)
// with:
//  - vectorized staging: interior positions load 6 f4 per image (y/z clamps
//    only shift row bases; x-taps are contiguous) instead of 18 scalars;
//    edge lanes (gx<3 or gx>123) keep the scalar tap path
//  - f2/packed epilogue stats (v_pk_add/sub/mul_f32)
//  - plain (non-atomic) flag load in the early-exit fallback — the round-8
//    agent-scope ACQUIRE forced per-wave L2 invalidates (XCD non-coherence)
//  - nested clamps preserved exactly; /27 dropped (exact: scale-invariant)

#define DIM 128
#define HW (128 * 128)
#define DHW (128 * 128 * 128)
#define NVOX (2 * DHW)
#define LOSS_COUNT (2.0 * 12.0 * DHW)

#define TS   16                   // tile side (y and x)
#define SY   18                   // xsum rows incl. y halo
#define NSP  (SY * TS)            // 288 xsum positions
#define CHZ  16                   // z-chunk per block
#define PSTR 7                    // f4 stride per position (6 used + 1 pad)
#define NBLK 1024                 // 128 x 8 grid

typedef float f4 __attribute__((ext_vector_type(4)));
typedef float f2 __attribute__((ext_vector_type(2)));

struct Header {                   // at d_ws+0, zeroed by memset each call
    unsigned counter0;            // fused completion counter
    unsigned counter1;            // dirty-path completion counter
    unsigned flag;                // 1 = clip binds (dirty)
    float m_p, m_t;
    unsigned pad;
    double acc_clip;              // clipped loss accumulator (dirty path)
};

struct Partial {                  // per-block slot at d_ws+256
    double vsump, vsumt, lsum;
    float mnp, mxp, mnt, mxt;
    float pad[6];                 // 64 B total
};

__device__ __forceinline__ int clampi(int v) {
    v = v < 0 ? 0 : v;
    return v > 127 ? 127 : v;
}

__device__ __forceinline__ f4 ld4(const float* p) {
    f4 v; __builtin_memcpy(&v, p, 16); return v;
}

struct SPos {
    int y0, ym, yp;          // row offsets * DIM (already clamped)
    int cx[3], cm[3], cp[3]; // per-wx tap columns (scalar/edge path)
    int gx;                  // raw column
    int woff;                // f4 index in LDS
    bool vec;                // interior-in-x: vector path legal
};

__device__ __forceinline__ SPos make_spos(int p, int y0t, int x0t, int stride) {
    SPos q;
    int py = p >> 4, px = p & 15;
    int gy = clampi(y0t - 1 + py);
    int gx = x0t + px;
    q.y0 = gy * DIM; q.ym = clampi(gy - 2) * DIM; q.yp = clampi(gy + 2) * DIM;
#pragma unroll
    for (int wx = 0; wx < 3; ++wx) {
        int c = clampi(gx + wx - 1);   // box tap clamp (outer pad)
        q.cx[wx] = c;
        q.cm[wx] = clampi(c - 2);      // dilation clamp (inner pad)
        q.cp[wx] = clampi(c + 2);
    }
    q.gx = gx;
    q.woff = p * stride;
    q.vec = (gx >= 3) && (gx <= 123);  // cL at gx-3, cR reads through gx+4
    return q;
}

// xsum for BOTH images at this position (packed f2); writes 6 f4.
__device__ __forceinline__ void stage_pair(const float* __restrict__ ip,
                                           const float* __restrict__ tp,
                                           int zm, int zc, int zp,
                                           const SPos& q, f4* __restrict__ X) {
    const int r0 = zm + q.y0, r1 = zc + q.y0, r2 = zc + q.ym;
    const int r3 = zc + q.yp, r4 = zp + q.y0;
    f2 acc[12];
#pragma unroll
    for (int c = 0; c < 12; ++c) acc[c] = (f2)0.0f;

    if (q.vec) {
        // contiguous x-taps: 6 f4 loads per image
        const int gx = q.gx;
        f4 pL = ld4(ip + r1 + gx - 3);   // cols gx-3..gx  (s1 taps = [0..2])
        f4 pR = ld4(ip + r1 + gx + 1);   // cols gx+1..gx+4 (s3 taps = [0..2])
        f4 p0 = ld4(ip + r0 + gx - 1);   // z-2 row, cols gx-1..gx+2
        f4 p2 = ld4(ip + r2 + gx - 1);   // y-2 row
        f4 p3 = ld4(ip + r3 + gx - 1);   // y+2 row
        f4 p4 = ld4(ip + r4 + gx - 1);   // z+2 row
        f4 tL = ld4(tp + r1 + gx - 3);
        f4 tR = ld4(tp + r1 + gx + 1);
        f4 t0 = ld4(tp + r0 + gx - 1);
        f4 t2 = ld4(tp + r2 + gx - 1);
        f4 t3 = ld4(tp + r3 + gx - 1);
        f4 t4 = ld4(tp + r4 + gx - 1);
#pragma unroll
        for (int wx = 0; wx < 3; ++wx) {
            f2 s0 = {p0[wx], t0[wx]};
            f2 s1 = {pL[wx], tL[wx]};
            f2 s2 = {p2[wx], t2[wx]};
            f2 s3 = {pR[wx], tR[wx]};
            f2 s4 = {p4[wx], t4[wx]};
            f2 s5 = {p3[wx], t3[wx]};
            f2 d;
            d = s1 - s0; acc[0]  += d * d;
            d = s2 - s0; acc[1]  += d * d;
            d = s2 - s1; acc[2]  += d * d;
            d = s3 - s0; acc[3]  += d * d;
            d = s3 - s2; acc[4]  += d * d;
            d = s4 - s1; acc[5]  += d * d;
            d = s4 - s2; acc[6]  += d * d;
            d = s4 - s3; acc[7]  += d * d;
            d = s5 - s0; acc[8]  += d * d;
            d = s5 - s1; acc[9]  += d * d;
            d = s5 - s3; acc[10] += d * d;
            d = s5 - s4; acc[11] += d * d;
        }
    } else {
        // x-edge lanes: clamped scalar taps (exact original path)
#pragma unroll
        for (int wx = 0; wx < 3; ++wx) {
            int o0 = r0 + q.cx[wx];
            int o1 = r1 + q.cm[wx];
            int o2 = r2 + q.cx[wx];
            int o3 = r1 + q.cp[wx];
            int o4 = r4 + q.cx[wx];
            int o5 = r3 + q.cx[wx];
            f2 s0 = {ip[o0], tp[o0]};
            f2 s1 = {ip[o1], tp[o1]};
            f2 s2 = {ip[o2], tp[o2]};
            f2 s3 = {ip[o3], tp[o3]};
            f2 s4 = {ip[o4], tp[o4]};
            f2 s5 = {ip[o5], tp[o5]};
            f2 d;
            d = s1 - s0; acc[0]  += d * d;
            d = s2 - s0; acc[1]  += d * d;
            d = s2 - s1; acc[2]  += d * d;
            d = s3 - s0; acc[3]  += d * d;
            d = s3 - s2; acc[4]  += d * d;
            d = s4 - s1; acc[5]  += d * d;
            d = s4 - s2; acc[6]  += d * d;
            d = s4 - s3; acc[7]  += d * d;
            d = s5 - s0; acc[8]  += d * d;
            d = s5 - s1; acc[9]  += d * d;
            d = s5 - s3; acc[10] += d * d;
            d = s5 - s4; acc[11] += d * d;
        }
    }
#pragma unroll
    for (int k = 0; k < 6; ++k) {
        f4 w;
        w.x = acc[2 * k].x;     w.y = acc[2 * k].y;
        w.z = acc[2 * k + 1].x; w.w = acc[2 * k + 1].y;
        X[q.woff + k] = w;
    }
}

__device__ __forceinline__ void box3y_pair(const f4* __restrict__ X,
                                           int ty, int tx, f4 q[6]) {
    int b0 = ((ty + 0) * TS + tx) * PSTR;
    int b1 = ((ty + 1) * TS + tx) * PSTR;
    int b2 = ((ty + 2) * TS + tx) * PSTR;
#pragma unroll
    for (int k = 0; k < 6; ++k)
        q[k] = X[b0 + k] + X[b1 + k] + X[b2 + k];
}

// single-image variants (clipped fallback path — rare, stays scalar)
__device__ __forceinline__ void stage_xsum(const float* __restrict__ im,
                                           int zm, int zc, int zp,
                                           const SPos& q, f4* __restrict__ P) {
    const int r0 = zm + q.y0, r1 = zc + q.y0, r2 = zc + q.ym;
    const int r3 = zc + q.yp, r4 = zp + q.y0;
    f4 a = (f4)0.0f, b = (f4)0.0f, c = (f4)0.0f;
#pragma unroll
    for (int wx = 0; wx < 3; ++wx) {
        float s0 = im[r0 + q.cx[wx]];
        float s1 = im[r1 + q.cm[wx]];
        float s2 = im[r2 + q.cx[wx]];
        float s3 = im[r1 + q.cp[wx]];
        float s4 = im[r4 + q.cx[wx]];
        float s5 = im[r3 + q.cx[wx]];
        float d;
        d = s1 - s0; a.x += d * d;
        d = s2 - s0; a.y += d * d;
        d = s2 - s1; a.z += d * d;
        d = s3 - s0; a.w += d * d;
        d = s3 - s2; b.x += d * d;
        d = s4 - s1; b.y += d * d;
        d = s4 - s2; b.z += d * d;
        d = s4 - s3; b.w += d * d;
        d = s5 - s0; c.x += d * d;
        d = s5 - s1; c.y += d * d;
        d = s5 - s3; c.z += d * d;
        d = s5 - s4; c.w += d * d;
    }
    P[q.woff + 0] = a;
    P[q.woff + 1] = b;
    P[q.woff + 2] = c;
}

__device__ __forceinline__ void box3y(const f4* __restrict__ P,
                                      int ty, int tx, f4 q[3]) {
    int base = (ty * TS + tx) * 3;
#pragma unroll
    for (int k = 0; k < 3; ++k)
        q[k] = P[base + k] + P[base + TS * 3 + k] + P[base + 2 * TS * 3 + k];
}

__device__ __forceinline__ float min12(const f4 v[3]) {
    float mn = v[0][0];
#pragma unroll
    for (int i = 0; i < 4; ++i)
        mn = fminf(mn, fminf(v[0][i], fminf(v[1][i], v[2][i])));
    return mn;
}
__device__ __forceinline__ float sum12(const f4 v[3]) {
    float sm = 0.0f;
#pragma unroll
    for (int i = 0; i < 4; ++i)
        sm += v[0][i] + v[1][i] + v[2][i];
    return sm;
}

// ======================  fused kernel + tail combine  ======================

__global__ __launch_bounds__(256, 4) void fused_kernel(const float* __restrict__ pred,
                                                       const float* __restrict__ targ,
                                                       Header* __restrict__ hdr,
                                                       Partial* __restrict__ parts,
                                                       float* __restrict__ out) {
    __shared__ f4 X[NSP * PSTR];

    const int t = threadIdx.x;
    const int tile = blockIdx.x & 63, n = blockIdx.x >> 6;
    const int x0t = (tile & 7) * TS, y0t = (tile >> 3) * TS;
    const int z0 = blockIdx.y * CHZ;
    const int bid = blockIdx.y * gridDim.x + blockIdx.x;
    const float* ip = pred + (size_t)n * DHW;
    const float* tp = targ + (size_t)n * DHW;

    SPos pa = make_spos(t, y0t, x0t, PSTR);
    const bool hasB = (t + 256) < NSP;
    SPos pb = make_spos(hasB ? (t + 256) : 0, y0t, x0t, PSTR);
    const int ty = t >> 4, tx = t & 15;

    f4 A[6], B[6];
#pragma unroll
    for (int k = 0; k < 6; ++k) { A[k] = (f4)0.0f; B[k] = (f4)0.0f; }

    float vsump = 0.0f, vsumt = 0.0f, lsum = 0.0f;
    float locmnp = 1e30f, locmxp = -1e30f, locmnt = 1e30f, locmxt = -1e30f;

    for (int tz = z0 - 1; tz <= z0 + CHZ; ++tz) {
        int zq = clampi(tz);
        int zc = zq * HW, zm = clampi(zq - 2) * HW, zp = clampi(zq + 2) * HW;
        stage_pair(ip, tp, zm, zc, zp, pa, X);
        if (hasB) stage_pair(ip, tp, zm, zc, zp, pb, X);
        __syncthreads();

        f4 q[6];
        box3y_pair(X, ty, tx, q);
        __syncthreads();

        int ze = tz - 1;
        if (ze >= z0) {
            f4 v[6];
#pragma unroll
            for (int k = 0; k < 6; ++k) v[k] = A[k] + q[k];

            // packed stats: lanes (pred,targ) in f2
            f2 sm2 = (f2)0.0f;
            float mnp = v[0][0], mnt = v[0][1];
#pragma unroll
            for (int k = 0; k < 6; ++k) {
                f2 a = {v[k].x, v[k].y};
                f2 b = {v[k].z, v[k].w};
                sm2 += a + b;
                mnp = fminf(mnp, fminf(v[k].x, v[k].z));
                mnt = fminf(mnt, fminf(v[k].y, v[k].w));
            }
            f2 mn2 = {mnp, mnt};
            f2 var2 = sm2 * (1.0f / 12.0f) - mn2;
            vsump += var2.x; vsumt += var2.y;
            locmnp = fminf(locmnp, var2.x); locmxp = fmaxf(locmxp, var2.x);
            locmnt = fminf(locmnt, var2.y); locmxt = fmaxf(locmxt, var2.y);

            f2 inv2 = {-1.0f / var2.x, -1.0f / var2.y};  // unclipped; validated below
            float la = 0.0f;
#pragma unroll
            for (int k = 0; k < 6; ++k) {
                f2 a = ({ f2 u = {v[k].x, v[k].y}; (u - mn2) * inv2; });
                f2 b = ({ f2 u = {v[k].z, v[k].w}; (u - mn2) * inv2; });
                float d0 = __expf(a.x) - __expf(a.y);
                float d1 = __expf(b.x) - __expf(b.y);
                la += d0 * d0 + d1 * d1;
            }
            lsum += la;
        }
#pragma unroll
        for (int k = 0; k < 6; ++k) { A[k] = B[k] + q[k]; B[k] = q[k]; }
    }

    // ---- per-block reduce of 7 quantities to thread 0 ----
#pragma unroll
    for (int off = 32; off > 0; off >>= 1) {
        vsump += __shfl_down(vsump, off, 64);
        vsumt += __shfl_down(vsumt, off, 64);
        lsum  += __shfl_down(lsum,  off, 64);
        locmnp = fminf(locmnp, __shfl_down(locmnp, off, 64));
        locmxp = fmaxf(locmxp, __shfl_down(locmxp, off, 64));
        locmnt = fminf(locmnt, __shfl_down(locmnt, off, 64));
        locmxt = fmaxf(locmxt, __shfl_down(locmxt, off, 64));
    }
    __shared__ float rs[4][7];
    __shared__ int s_tail;
    {
        int lane = t & 63, wid = t >> 6;
        if (lane == 0) {
            rs[wid][0] = vsump; rs[wid][1] = vsumt; rs[wid][2] = lsum;
            rs[wid][3] = locmnp; rs[wid][4] = locmxp;
            rs[wid][5] = locmnt; rs[wid][6] = locmxt;
        }
    }
    __syncthreads();
    if (t == 0) {
        double d0 = (double)rs[0][0] + rs[1][0] + rs[2][0] + rs[3][0];
        double d1 = (double)rs[0][1] + rs[1][1] + rs[2][1] + rs[3][1];
        double d2 = (double)rs[0][2] + rs[1][2] + rs[2][2] + rs[3][2];
        float a = fminf(fminf(rs[0][3], rs[1][3]), fminf(rs[2][3], rs[3][3]));
        float b = fmaxf(fmaxf(rs[0][4], rs[1][4]), fmaxf(rs[2][4], rs[3][4]));
        float c = fminf(fminf(rs[0][5], rs[1][5]), fminf(rs[2][5], rs[3][5]));
        float d = fmaxf(fmaxf(rs[0][6], rs[1][6]), fmaxf(rs[2][6], rs[3][6]));
        Partial* p = &parts[bid];
        __hip_atomic_store(&p->vsump, d0, __ATOMIC_RELAXED, __HIP_MEMORY_SCOPE_AGENT);
        __hip_atomic_store(&p->vsumt, d1, __ATOMIC_RELAXED, __HIP_MEMORY_SCOPE_AGENT);
        __hip_atomic_store(&p->lsum,  d2, __ATOMIC_RELAXED, __HIP_MEMORY_SCOPE_AGENT);
        __hip_atomic_store(&p->mnp, a, __ATOMIC_RELAXED, __HIP_MEMORY_SCOPE_AGENT);
        __hip_atomic_store(&p->mxp, b, __ATOMIC_RELAXED, __HIP_MEMORY_SCOPE_AGENT);
        __hip_atomic_store(&p->mnt, c, __ATOMIC_RELAXED, __HIP_MEMORY_SCOPE_AGENT);
        __hip_atomic_store(&p->mxt, d, __ATOMIC_RELAXED, __HIP_MEMORY_SCOPE_AGENT);
        unsigned old = __hip_atomic_fetch_add(&hdr->counter0, 1u,
                                              __ATOMIC_ACQ_REL, __HIP_MEMORY_SCOPE_AGENT);
        s_tail = (old == NBLK - 1) ? 1 : 0;
    }
    __syncthreads();

    // ---- last-finishing block: combine all partials, flag, maybe finalize ----
    if (s_tail) {
        double vp = 0.0, vt = 0.0, ls = 0.0;
        float mnp = 1e30f, mxp = -1e30f, mnt = 1e30f, mxt = -1e30f;
        for (int b = t; b < NBLK; b += 256) {
            const Partial* p = &parts[b];
            vp += __hip_atomic_load(&p->vsump, __ATOMIC_RELAXED, __HIP_MEMORY_SCOPE_AGENT);
            vt += __hip_atomic_load(&p->vsumt, __ATOMIC_RELAXED, __HIP_MEMORY_SCOPE_AGENT);
            ls += __hip_atomic_load(&p->lsum,  __ATOMIC_RELAXED, __HIP_MEMORY_SCOPE_AGENT);
            mnp = fminf(mnp, __hip_atomic_load(&p->mnp, __ATOMIC_RELAXED, __HIP_MEMORY_SCOPE_AGENT));
            mxp = fmaxf(mxp, __hip_atomic_load(&p->mxp, __ATOMIC_RELAXED, __HIP_MEMORY_SCOPE_AGENT));
            mnt = fminf(mnt, __hip_atomic_load(&p->mnt, __ATOMIC_RELAXED, __HIP_MEMORY_SCOPE_AGENT));
            mxt = fmaxf(mxt, __hip_atomic_load(&p->mxt, __ATOMIC_RELAXED, __HIP_MEMORY_SCOPE_AGENT));
        }
#pragma unroll
        for (int off = 32; off > 0; off >>= 1) {
            vp += __shfl_down(vp, off, 64);
            vt += __shfl_down(vt, off, 64);
            ls += __shfl_down(ls, off, 64);
            mnp = fminf(mnp, __shfl_down(mnp, off, 64));
            mxp = fmaxf(mxp, __shfl_down(mxp, off, 64));
            mnt = fminf(mnt, __shfl_down(mnt, off, 64));
            mxt = fmaxf(mxt, __shfl_down(mxt, off, 64));
        }
        __shared__ double rd[4][3];
        __shared__ float rf[4][4];
        int lane = t & 63, wid = t >> 6;
        if (lane == 0) {
            rd[wid][0] = vp; rd[wid][1] = vt; rd[wid][2] = ls;
            rf[wid][0] = mnp; rf[wid][1] = mxp; rf[wid][2] = mnt; rf[wid][3] = mxt;
        }
        __syncthreads();
        if (t == 0) {
            double VP = rd[0][0] + rd[1][0] + rd[2][0] + rd[3][0];
            double VT = rd[0][1] + rd[1][1] + rd[2][1] + rd[3][1];
            double LS = rd[0][2] + rd[1][2] + rd[2][2] + rd[3][2];
            float MNP = fminf(fminf(rf[0][0], rf[1][0]), fminf(rf[2][0], rf[3][0]));
            float MXP = fmaxf(fmaxf(rf[0][1], rf[1][1]), fmaxf(rf[2][1], rf[3][1]));
            float MNT = fminf(fminf(rf[0][2], rf[1][2]), fminf(rf[2][2], rf[3][2]));
            float MXT = fmaxf(fmaxf(rf[0][3], rf[1][3]), fmaxf(rf[2][3], rf[3][3]));
            float m_p = (float)(VP * (1.0 / (double)NVOX));
            float m_t = (float)(VT * (1.0 / (double)NVOX));
            // clip leaves v unchanged iff lo <= v <= hi (same fp exprs as fallback)
            bool clean = (MNP >= m_p * 0.001f) && (MXP <= m_p * 1000.0f) &&
                         (MNT >= m_t * 0.001f) && (MXT <= m_t * 1000.0f);
            hdr->m_p = m_p;
            hdr->m_t = m_t;
            __hip_atomic_store(&hdr->acc_clip, 0.0, __ATOMIC_RELAXED, __HIP_MEMORY_SCOPE_AGENT);
            __hip_atomic_store(&hdr->flag, clean ? 0u : 1u,
                               __ATOMIC_RELEASE, __HIP_MEMORY_SCOPE_AGENT);
            if (clean) out[0] = (float)(LS * (1.0 / LOSS_COUNT));
        }
    }
}

// =================  clipped fallback (only if clip binds)  =================

__global__ __launch_bounds__(256, 4) void loss_kernel(const float* __restrict__ pred,
                                                      const float* __restrict__ targ,
                                                      Header* __restrict__ hdr,
                                                      float* __restrict__ out) {
    // plain load: ordering vs fused_kernel is guaranteed by the dispatch
    // boundary; an agent-scope acquire here costs an L2 invalidate per wave.
    if (*(volatile const unsigned*)&hdr->flag == 0u)
        return;   // block-uniform; expected path

    __shared__ f4 Xp[NSP * 3];
    __shared__ f4 Xt[NSP * 3];
    const int t = threadIdx.x;
    const int tile = blockIdx.x & 63, n = blockIdx.x >> 6;
    const int x0t = (tile & 7) * TS, y0t = (tile >> 3) * TS;
    const int z0 = blockIdx.y * CHZ;
    const float* ip = pred + (size_t)n * DHW;
    const float* tp = targ + (size_t)n * DHW;

    const float m_p = hdr->m_p;
    const float m_t = hdr->m_t;

    SPos pa = make_spos(t, y0t, x0t, 3);
    const bool hasB = (t + 256) < NSP;
    SPos pb = make_spos(hasB ? (t + 256) : 0, y0t, x0t, 3);
    const int ty = t >> 4, tx = t & 15;

    f4 Ap[3], Bp[3], At[3], Bt[3];
#pragma unroll
    for (int q = 0; q < 3; ++q) {
        Ap[q] = (f4)0.0f; Bp[q] = (f4)0.0f;
        At[q] = (f4)0.0f; Bt[q] = (f4)0.0f;
    }
    float lsum = 0.0f;

    for (int tz = z0 - 1; tz <= z0 + CHZ; ++tz) {
        int zq = clampi(tz);
        int zc = zq * HW, zm = clampi(zq - 2) * HW, zp = clampi(zq + 2) * HW;
        stage_xsum(ip, zm, zc, zp, pa, Xp);
        stage_xsum(tp, zm, zc, zp, pa, Xt);
        if (hasB) {
            stage_xsum(ip, zm, zc, zp, pb, Xp);
            stage_xsum(tp, zm, zc, zp, pb, Xt);
        }
        __syncthreads();

        f4 qp[3], qt[3];
        box3y(Xp, ty, tx, qp);
        box3y(Xt, ty, tx, qt);
        __syncthreads();

        int ze = tz - 1;
        if (ze >= z0) {
            f4 vp[3], vt[3];
#pragma unroll
            for (int q = 0; q < 3; ++q) {
                vp[q] = Ap[q] + qp[q];
                vt[q] = At[q] + qt[q];
            }
            float mnp = min12(vp), smp = sum12(vp);
            float mnt = min12(vt), smt = sum12(vt);
            float varp = smp * (1.0f / 12.0f) - mnp;
            varp = fminf(fmaxf(varp, m_p * 0.001f), m_p * 1000.0f);
            float invp = -1.0f / varp;
            float vart = smt * (1.0f / 12.0f) - mnt;
            vart = fminf(fmaxf(vart, m_t * 0.001f), m_t * 1000.0f);
            float invt = -1.0f / vart;

            float a = 0.0f;
#pragma unroll
            for (int q = 0; q < 3; ++q)
#pragma unroll
                for (int i = 0; i < 4; ++i) {
                    float ep = __expf((vp[q][i] - mnp) * invp);
                    float et = __expf((vt[q][i] - mnt) * invt);
                    float dd = ep - et;
                    a += dd * dd;
                }
            lsum += a;
        }
#pragma unroll
        for (int q = 0; q < 3; ++q) {
            Ap[q] = Bp[q] + qp[q]; Bp[q] = qp[q];
            At[q] = Bt[q] + qt[q]; Bt[q] = qt[q];
        }
    }

    // block reduce -> device accumulate -> last block writes out
#pragma unroll
    for (int off = 32; off > 0; off >>= 1)
        lsum += __shfl_down(lsum, off, 64);
    __shared__ float red[4];
    int lane = t & 63, wid = t >> 6;
    if (lane == 0) red[wid] = lsum;
    __syncthreads();
    if (t == 0) {
        double tt = (double)red[0] + red[1] + red[2] + red[3];
        atomicAdd(&hdr->acc_clip, tt);
        unsigned old = __hip_atomic_fetch_add(&hdr->counter1, 1u,
                                              __ATOMIC_ACQ_REL, __HIP_MEMORY_SCOPE_AGENT);
        if (old == NBLK - 1) {
            double l = __hip_atomic_load(&hdr->acc_clip, __ATOMIC_RELAXED,
                                         __HIP_MEMORY_SCOPE_AGENT);
            out[0] = (float)(l * (1.0 / LOSS_COUNT));
        }
    }
}

extern "C" void kernel_launch(void* const* d_in, const int* in_sizes, int n_in,
                              void* d_out, int out_size, void* d_ws, size_t ws_size,
                              hipStream_t stream) {
    const float* pred = (const float*)d_in[0];
    const float* targ = (const float*)d_in[1];
    float* out = (float*)d_out;
    Header* hdr = (Header*)d_ws;
    Partial* parts = (Partial*)((char*)d_ws + 256);

    hipMemsetAsync(d_ws, 0, 256, stream);

    dim3 block(256);
    dim3 grid(128, 8);   // 64 tiles * 2 batch, 8 z-chunks of 16 = 1024 blocks
    fused_kernel<<<grid, block, 0, stream>>>(pred, targ, hdr, parts, out);
    loss_kernel<<<grid, block, 0, stream>>>(pred, targ, hdr, out);
}

// Round 10
// 169.878 us; speedup vs baseline: 1.9241x; 1.9241x over previous
//
#include <hip/hip_runtime.h>

// MIND-SSC loss, N=2, C=1, D=H=W=128, radius=1, dilation=2.
// Round 10: revert to proven round-6/8 fused shape; minimal coordination.
//  graph = memset(96B) + fused_kernel + loss_kernel(inline flag, early-exit)
//  - fused: scalar x-folded staging (VGPR 64, no spill — round-9's vector
//    staging spilled 344 MB to scratch), packed f2 epilogue, plain double
//    atomicAdd + complemented-key minmax atomics (memset-0 is valid init)
//  - loss_kernel: every block recomputes the exact clip-binding flag from
//    acc/keys (deterministic -> uniform); clean => block0 writes out, exit;
//    dirty => full clipped recompute + counter finalize
//  - nested clamps preserved exactly; /27 dropped (exact: scale-invariant)

#define DIM 128
#define HW (128 * 128)
#define DHW (128 * 128 * 128)
#define NVOX (2 * DHW)
#define LOSS_COUNT (2.0 * 12.0 * DHW)

#define TS   16                   // tile side (y and x)
#define SY   18                   // xsum rows incl. y halo
#define NSP  (SY * TS)            // 288 xsum positions
#define CHZ  16                   // z-chunk per block
#define PSTR 7                    // f4 stride per position (6 used + 1 pad)
#define NBLK 1024                 // 128 x 8 grid

typedef float f4 __attribute__((ext_vector_type(4)));
typedef float f2 __attribute__((ext_vector_type(2)));

// d_ws layout (all zeroed by the 96-B memset):
//   double acc[4]: vsum_p, vsum_t, loss_unclip, loss_clip      (offset 0)
//   unsigned keys[8] at offset 64:
//     [0] = max(~fkey(var_p))  -> tracks MIN var_p   (0-init valid)
//     [1] = max( fkey(var_p))  -> tracks MAX var_p
//     [2] = max(~fkey(var_t))  -> tracks MIN var_t
//     [3] = max( fkey(var_t))  -> tracks MAX var_t
//     [4] = dirty-path completion counter

__device__ __forceinline__ int clampi(int v) {
    v = v < 0 ? 0 : v;
    return v > 127 ? 127 : v;
}

__device__ __forceinline__ unsigned fkey(float f) {
    unsigned u = __float_as_uint(f);
    return (u & 0x80000000u) ? ~u : (u | 0x80000000u);
}
__device__ __forceinline__ float fdec(unsigned k) {
    unsigned u = (k & 0x80000000u) ? (k ^ 0x80000000u) : ~k;
    return __uint_as_float(u);
}

__device__ __forceinline__ void block_reduce_atomic(float v, double* dst) {
#pragma unroll
    for (int off = 32; off > 0; off >>= 1)
        v += __shfl_down(v, off, 64);
    __shared__ float red[4];
    int lane = threadIdx.x & 63;
    int wid  = threadIdx.x >> 6;
    if (lane == 0) red[wid] = v;
    __syncthreads();
    if (threadIdx.x == 0) {
        double t = (double)red[0] + (double)red[1] + (double)red[2] + (double)red[3];
        atomicAdd(dst, t);
    }
    __syncthreads();
}

__device__ __forceinline__ void block_minmax_atomic(float mnp, float mxp,
                                                    float mnt, float mxt,
                                                    unsigned* keys) {
#pragma unroll
    for (int off = 32; off > 0; off >>= 1) {
        mnp = fminf(mnp, __shfl_down(mnp, off, 64));
        mxp = fmaxf(mxp, __shfl_down(mxp, off, 64));
        mnt = fminf(mnt, __shfl_down(mnt, off, 64));
        mxt = fmaxf(mxt, __shfl_down(mxt, off, 64));
    }
    __shared__ float r[4][4];
    int lane = threadIdx.x & 63, wid = threadIdx.x >> 6;
    if (lane == 0) { r[wid][0] = mnp; r[wid][1] = mxp; r[wid][2] = mnt; r[wid][3] = mxt; }
    __syncthreads();
    if (threadIdx.x == 0) {
        float a = fminf(fminf(r[0][0], r[1][0]), fminf(r[2][0], r[3][0]));
        float b = fmaxf(fmaxf(r[0][1], r[1][1]), fmaxf(r[2][1], r[3][1]));
        float c = fminf(fminf(r[0][2], r[1][2]), fminf(r[2][2], r[3][2]));
        float d = fmaxf(fmaxf(r[0][3], r[1][3]), fmaxf(r[2][3], r[3][3]));
        atomicMax(&keys[0], ~fkey(a));   // min via complemented key
        atomicMax(&keys[1],  fkey(b));
        atomicMax(&keys[2], ~fkey(c));
        atomicMax(&keys[3],  fkey(d));
    }
    __syncthreads();
}

struct SPos {
    int y0, ym, yp;          // row offsets * DIM (already clamped)
    int cx[3], cm[3], cp[3]; // per-wx tap columns
    int woff;                // f4 index in LDS
};

__device__ __forceinline__ SPos make_spos(int p, int y0t, int x0t, int stride) {
    SPos q;
    int py = p >> 4, px = p & 15;
    int gy = clampi(y0t - 1 + py);
    int gx = x0t + px;
    q.y0 = gy * DIM; q.ym = clampi(gy - 2) * DIM; q.yp = clampi(gy + 2) * DIM;
#pragma unroll
    for (int wx = 0; wx < 3; ++wx) {
        int c = clampi(gx + wx - 1);   // box tap clamp (outer pad)
        q.cx[wx] = c;
        q.cm[wx] = clampi(c - 2);      // dilation clamp (inner pad)
        q.cp[wx] = clampi(c + 2);
    }
    q.woff = p * stride;
    return q;
}

// xsum for BOTH images at this position (packed f2); writes 6 f4.
__device__ __forceinline__ void stage_pair(const float* __restrict__ ip,
                                           const float* __restrict__ tp,
                                           int zm, int zc, int zp,
                                           const SPos& q, f4* __restrict__ X) {
    const int r0 = zm + q.y0, r1 = zc + q.y0, r2 = zc + q.ym;
    const int r3 = zc + q.yp, r4 = zp + q.y0;
    f2 acc[12];
#pragma unroll
    for (int c = 0; c < 12; ++c) acc[c] = (f2)0.0f;
#pragma unroll
    for (int wx = 0; wx < 3; ++wx) {
        int o0 = r0 + q.cx[wx];
        int o1 = r1 + q.cm[wx];
        int o2 = r2 + q.cx[wx];
        int o3 = r1 + q.cp[wx];
        int o4 = r4 + q.cx[wx];
        int o5 = r3 + q.cx[wx];
        f2 s0 = {ip[o0], tp[o0]};
        f2 s1 = {ip[o1], tp[o1]};
        f2 s2 = {ip[o2], tp[o2]};
        f2 s3 = {ip[o3], tp[o3]};
        f2 s4 = {ip[o4], tp[o4]};
        f2 s5 = {ip[o5], tp[o5]};
        f2 d;
        d = s1 - s0; acc[0]  += d * d;
        d = s2 - s0; acc[1]  += d * d;
        d = s2 - s1; acc[2]  += d * d;
        d = s3 - s0; acc[3]  += d * d;
        d = s3 - s2; acc[4]  += d * d;
        d = s4 - s1; acc[5]  += d * d;
        d = s4 - s2; acc[6]  += d * d;
        d = s4 - s3; acc[7]  += d * d;
        d = s5 - s0; acc[8]  += d * d;
        d = s5 - s1; acc[9]  += d * d;
        d = s5 - s3; acc[10] += d * d;
        d = s5 - s4; acc[11] += d * d;
    }
#pragma unroll
    for (int k = 0; k < 6; ++k) {
        f4 w;
        w.x = acc[2 * k].x;     w.y = acc[2 * k].y;
        w.z = acc[2 * k + 1].x; w.w = acc[2 * k + 1].y;
        X[q.woff + k] = w;
    }
}

__device__ __forceinline__ void box3y_pair(const f4* __restrict__ X,
                                           int ty, int tx, f4 q[6]) {
    int b0 = ((ty + 0) * TS + tx) * PSTR;
    int b1 = ((ty + 1) * TS + tx) * PSTR;
    int b2 = ((ty + 2) * TS + tx) * PSTR;
#pragma unroll
    for (int k = 0; k < 6; ++k)
        q[k] = X[b0 + k] + X[b1 + k] + X[b2 + k];
}

// single-image variants (clipped fallback path)
__device__ __forceinline__ void stage_xsum(const float* __restrict__ im,
                                           int zm, int zc, int zp,
                                           const SPos& q, f4* __restrict__ P) {
    const int r0 = zm + q.y0, r1 = zc + q.y0, r2 = zc + q.ym;
    const int r3 = zc + q.yp, r4 = zp + q.y0;
    f4 a = (f4)0.0f, b = (f4)0.0f, c = (f4)0.0f;
#pragma unroll
    for (int wx = 0; wx < 3; ++wx) {
        float s0 = im[r0 + q.cx[wx]];
        float s1 = im[r1 + q.cm[wx]];
        float s2 = im[r2 + q.cx[wx]];
        float s3 = im[r1 + q.cp[wx]];
        float s4 = im[r4 + q.cx[wx]];
        float s5 = im[r3 + q.cx[wx]];
        float d;
        d = s1 - s0; a.x += d * d;
        d = s2 - s0; a.y += d * d;
        d = s2 - s1; a.z += d * d;
        d = s3 - s0; a.w += d * d;
        d = s3 - s2; b.x += d * d;
        d = s4 - s1; b.y += d * d;
        d = s4 - s2; b.z += d * d;
        d = s4 - s3; b.w += d * d;
        d = s5 - s0; c.x += d * d;
        d = s5 - s1; c.y += d * d;
        d = s5 - s3; c.z += d * d;
        d = s5 - s4; c.w += d * d;
    }
    P[q.woff + 0] = a;
    P[q.woff + 1] = b;
    P[q.woff + 2] = c;
}

__device__ __forceinline__ void box3y(const f4* __restrict__ P,
                                      int ty, int tx, f4 q[3]) {
    int base = (ty * TS + tx) * 3;
#pragma unroll
    for (int k = 0; k < 3; ++k)
        q[k] = P[base + k] + P[base + TS * 3 + k] + P[base + 2 * TS * 3 + k];
}

__device__ __forceinline__ float min12(const f4 v[3]) {
    float mn = v[0][0];
#pragma unroll
    for (int i = 0; i < 4; ++i)
        mn = fminf(mn, fminf(v[0][i], fminf(v[1][i], v[2][i])));
    return mn;
}
__device__ __forceinline__ float sum12(const f4 v[3]) {
    float sm = 0.0f;
#pragma unroll
    for (int i = 0; i < 4; ++i)
        sm += v[0][i] + v[1][i] + v[2][i];
    return sm;
}

// ==========================  fused kernel  ================================

__global__ __launch_bounds__(256, 4) void fused_kernel(const float* __restrict__ pred,
                                                       const float* __restrict__ targ,
                                                       double* __restrict__ acc,
                                                       unsigned* __restrict__ keys) {
    __shared__ f4 X[NSP * PSTR];

    const int t = threadIdx.x;
    const int tile = blockIdx.x & 63, n = blockIdx.x >> 6;
    const int x0t = (tile & 7) * TS, y0t = (tile >> 3) * TS;
    const int z0 = blockIdx.y * CHZ;
    const float* ip = pred + (size_t)n * DHW;
    const float* tp = targ + (size_t)n * DHW;

    SPos pa = make_spos(t, y0t, x0t, PSTR);
    const bool hasB = (t + 256) < NSP;
    SPos pb = make_spos(hasB ? (t + 256) : 0, y0t, x0t, PSTR);
    const int ty = t >> 4, tx = t & 15;

    f4 A[6], B[6];
#pragma unroll
    for (int k = 0; k < 6; ++k) { A[k] = (f4)0.0f; B[k] = (f4)0.0f; }

    float vsump = 0.0f, vsumt = 0.0f, lsum = 0.0f;
    float locmnp = 1e30f, locmxp = -1e30f, locmnt = 1e30f, locmxt = -1e30f;

    for (int tz = z0 - 1; tz <= z0 + CHZ; ++tz) {
        int zq = clampi(tz);
        int zc = zq * HW, zm = clampi(zq - 2) * HW, zp = clampi(zq + 2) * HW;
        stage_pair(ip, tp, zm, zc, zp, pa, X);
        if (hasB) stage_pair(ip, tp, zm, zc, zp, pb, X);
        __syncthreads();

        f4 q[6];
        box3y_pair(X, ty, tx, q);
        __syncthreads();

        int ze = tz - 1;
        if (ze >= z0) {
            f4 v[6];
#pragma unroll
            for (int k = 0; k < 6; ++k) v[k] = A[k] + q[k];

            // packed stats: lanes (pred,targ) in f2
            f2 sm2 = (f2)0.0f;
            float mnp = v[0][0], mnt = v[0][1];
#pragma unroll
            for (int k = 0; k < 6; ++k) {
                f2 a = {v[k].x, v[k].y};
                f2 b = {v[k].z, v[k].w};
                sm2 += a + b;
                mnp = fminf(mnp, fminf(v[k].x, v[k].z));
                mnt = fminf(mnt, fminf(v[k].y, v[k].w));
            }
            f2 mn2 = {mnp, mnt};
            f2 var2 = sm2 * (1.0f / 12.0f) - mn2;
            vsump += var2.x; vsumt += var2.y;
            locmnp = fminf(locmnp, var2.x); locmxp = fmaxf(locmxp, var2.x);
            locmnt = fminf(locmnt, var2.y); locmxt = fmaxf(locmxt, var2.y);

            f2 inv2 = {-1.0f / var2.x, -1.0f / var2.y};  // unclipped; validated later
            float la = 0.0f;
#pragma unroll
            for (int k = 0; k < 6; ++k) {
                f2 a = ({ f2 u = {v[k].x, v[k].y}; (u - mn2) * inv2; });
                f2 b = ({ f2 u = {v[k].z, v[k].w}; (u - mn2) * inv2; });
                float d0 = __expf(a.x) - __expf(a.y);
                float d1 = __expf(b.x) - __expf(b.y);
                la += d0 * d0 + d1 * d1;
            }
            lsum += la;
        }
#pragma unroll
        for (int k = 0; k < 6; ++k) { A[k] = B[k] + q[k]; B[k] = q[k]; }
    }

    block_reduce_atomic(vsump, &acc[0]);
    block_reduce_atomic(vsumt, &acc[1]);
    block_reduce_atomic(lsum,  &acc[2]);
    block_minmax_atomic(locmnp, locmxp, locmnt, locmxt, keys);
}

// ============  loss kernel: inline flag; clean => write & exit  ============

__global__ __launch_bounds__(256, 4) void loss_kernel(const float* __restrict__ pred,
                                                      const float* __restrict__ targ,
                                                      double* __restrict__ acc,
                                                      unsigned* __restrict__ keys,
                                                      float* __restrict__ out) {
    __shared__ float s_m[2];
    __shared__ int s_clean;
    const int t = threadIdx.x;
    if (t == 0) {
        // plain loads: visibility across the dispatch boundary is implicit
        float m_p = (float)(acc[0] * (1.0 / (double)NVOX));
        float m_t = (float)(acc[1] * (1.0 / (double)NVOX));
        float mnp = fdec(~keys[0]), mxp = fdec(keys[1]);
        float mnt = fdec(~keys[2]), mxt = fdec(keys[3]);
        // clip leaves v unchanged iff lo <= v <= hi (same fp exprs as below)
        bool clean = (mnp >= m_p * 0.001f) && (mxp <= m_p * 1000.0f) &&
                     (mnt >= m_t * 0.001f) && (mxt <= m_t * 1000.0f);
        s_m[0] = m_p; s_m[1] = m_t; s_clean = clean ? 1 : 0;
    }
    __syncthreads();

    if (s_clean) {   // expected path: deterministic, uniform over all blocks
        if (blockIdx.x == 0 && blockIdx.y == 0 && t == 0)
            out[0] = (float)(acc[2] * (1.0 / LOSS_COUNT));
        return;
    }

    // ------- dirty path: full clipped recompute (rare/never for these inputs)
    const float m_p = s_m[0], m_t = s_m[1];

    __shared__ f4 Xp[NSP * 3];
    __shared__ f4 Xt[NSP * 3];
    const int tile = blockIdx.x & 63, n = blockIdx.x >> 6;
    const int x0t = (tile & 7) * TS, y0t = (tile >> 3) * TS;
    const int z0 = blockIdx.y * CHZ;
    const float* ip = pred + (size_t)n * DHW;
    const float* tp = targ + (size_t)n * DHW;

    SPos pa = make_spos(t, y0t, x0t, 3);
    const bool hasB = (t + 256) < NSP;
    SPos pb = make_spos(hasB ? (t + 256) : 0, y0t, x0t, 3);
    const int ty = t >> 4, tx = t & 15;

    f4 Ap[3], Bp[3], At[3], Bt[3];
#pragma unroll
    for (int q = 0; q < 3; ++q) {
        Ap[q] = (f4)0.0f; Bp[q] = (f4)0.0f;
        At[q] = (f4)0.0f; Bt[q] = (f4)0.0f;
    }
    float lsum = 0.0f;

    for (int tz = z0 - 1; tz <= z0 + CHZ; ++tz) {
        int zq = clampi(tz);
        int zc = zq * HW, zm = clampi(zq - 2) * HW, zp = clampi(zq + 2) * HW;
        stage_xsum(ip, zm, zc, zp, pa, Xp);
        stage_xsum(tp, zm, zc, zp, pa, Xt);
        if (hasB) {
            stage_xsum(ip, zm, zc, zp, pb, Xp);
            stage_xsum(tp, zm, zc, zp, pb, Xt);
        }
        __syncthreads();

        f4 qp[3], qt[3];
        box3y(Xp, ty, tx, qp);
        box3y(Xt, ty, tx, qt);
        __syncthreads();

        int ze = tz - 1;
        if (ze >= z0) {
            f4 vp[3], vt[3];
#pragma unroll
            for (int q = 0; q < 3; ++q) {
                vp[q] = Ap[q] + qp[q];
                vt[q] = At[q] + qt[q];
            }
            float mnp = min12(vp), smp = sum12(vp);
            float mnt = min12(vt), smt = sum12(vt);
            float varp = smp * (1.0f / 12.0f) - mnp;
            varp = fminf(fmaxf(varp, m_p * 0.001f), m_p * 1000.0f);
            float invp = -1.0f / varp;
            float vart = smt * (1.0f / 12.0f) - mnt;
            vart = fminf(fmaxf(vart, m_t * 0.001f), m_t * 1000.0f);
            float invt = -1.0f / vart;

            float a = 0.0f;
#pragma unroll
            for (int q = 0; q < 3; ++q)
#pragma unroll
                for (int i = 0; i < 4; ++i) {
                    float ep = __expf((vp[q][i] - mnp) * invp);
                    float et = __expf((vt[q][i] - mnt) * invt);
                    float dd = ep - et;
                    a += dd * dd;
                }
            lsum += a;
        }
#pragma unroll
        for (int q = 0; q < 3; ++q) {
            Ap[q] = Bp[q] + qp[q]; Bp[q] = qp[q];
            At[q] = Bt[q] + qt[q]; Bt[q] = qt[q];
        }
    }

    // block reduce -> device accumulate -> last block writes out
#pragma unroll
    for (int off = 32; off > 0; off >>= 1)
        lsum += __shfl_down(lsum, off, 64);
    __shared__ float red[4];
    int lane = t & 63, wid = t >> 6;
    if (lane == 0) red[wid] = lsum;
    __syncthreads();
    if (t == 0) {
        double tt = (double)red[0] + red[1] + red[2] + red[3];
        atomicAdd(&acc[3], tt);
        unsigned old = atomicAdd(&keys[4], 1u);
        if (old == NBLK - 1) {
            double l = __hip_atomic_load(&acc[3], __ATOMIC_RELAXED,
                                         __HIP_MEMORY_SCOPE_AGENT);
            out[0] = (float)(l * (1.0 / LOSS_COUNT));
        }
    }
}

extern "C" void kernel_launch(void* const* d_in, const int* in_sizes, int n_in,
                              void* d_out, int out_size, void* d_ws, size_t ws_size,
                              hipStream_t stream) {
    const float* pred = (const float*)d_in[0];
    const float* targ = (const float*)d_in[1];
    float* out = (float*)d_out;
    double* acc = (double*)d_ws;
    unsigned* keys = (unsigned*)((char*)d_ws + 64);

    hipMemsetAsync(d_ws, 0, 96, stream);

    dim3 block(256);
    dim3 grid(128, 8);   // 64 tiles * 2 batch, 8 z-chunks of 16 = 1024 blocks
    fused_kernel<<<grid, block, 0, stream>>>(pred, targ, acc, keys);
    loss_kernel<<<grid, block, 0, stream>>>(pred, targ, acc, keys, out);
}